// Round 1
// baseline (26.014 us; speedup 1.0000x reference)
//
#include <hip/hip_runtime.h>
#include <hip/hip_bf16.h>

// Quantum layer: 4 qubits, 2 layers. Everything after the RY(x) encoding is a
// fixed unitary U (weights are batch-constant). evs_q(x) = s^T Re(M_q) s with
// s the real product state from RY encoding; since v v^T spans (1,cos t,sin t)
// per qubit, evs_q is multilinear with 81 coefficients per output.
// Setup kernel (4 blocks) computes C[4][81] from weights into d_ws.
// Main kernel evaluates 4 polynomials per element (B = 1M).

__global__ __launch_bounds__(256) void qsetup(const float* __restrict__ w,
                                              float* __restrict__ C) {
    __shared__ float Ur[16][16];   // [row k][col j]
    __shared__ float Ui[16][16];
    __shared__ float M[16][16];
    const int q = blockIdx.x;      // output qubit 0..3
    const int tid = threadIdx.x;

    // ---- step 1: threads 0..15 each simulate one basis column of U ----
    if (tid < 16) {
        float re[16], im[16];
#pragma unroll
        for (int i = 0; i < 16; ++i) { re[i] = (i == tid) ? 1.0f : 0.0f; im[i] = 0.0f; }

#pragma unroll
        for (int ly = 0; ly < 2; ++ly) {
#pragma unroll
            for (int qq = 0; qq < 4; ++qq) {
                const int mm = 8 >> qq;
                float th, c, s;
                // RX(w[ly][qq][0])
                th = w[(ly * 4 + qq) * 3 + 0] * 0.5f; c = __cosf(th); s = __sinf(th);
#pragma unroll
                for (int i = 0; i < 16; ++i) if (!(i & mm)) {
                    const int j = i | mm;
                    float r0 = re[i], i0 = im[i], r1 = re[j], i1 = im[j];
                    re[i] = c * r0 + s * i1;  im[i] = c * i0 - s * r1;
                    re[j] = s * i0 + c * r1;  im[j] = -s * r0 + c * i1;
                }
                // RY(w[ly][qq][1])
                th = w[(ly * 4 + qq) * 3 + 1] * 0.5f; c = __cosf(th); s = __sinf(th);
#pragma unroll
                for (int i = 0; i < 16; ++i) if (!(i & mm)) {
                    const int j = i | mm;
                    float r0 = re[i], i0 = im[i], r1 = re[j], i1 = im[j];
                    re[i] = c * r0 - s * r1;  im[i] = c * i0 - s * i1;
                    re[j] = s * r0 + c * r1;  im[j] = s * i0 + c * i1;
                }
                // RZ(w[ly][qq][2])
                th = w[(ly * 4 + qq) * 3 + 2] * 0.5f; c = __cosf(th); s = __sinf(th);
#pragma unroll
                for (int i = 0; i < 16; ++i) if (!(i & mm)) {
                    const int j = i | mm;
                    float r0 = re[i], i0 = im[i], r1 = re[j], i1 = im[j];
                    re[i] = c * r0 + s * i0;  im[i] = c * i0 - s * r0;
                    re[j] = c * r1 - s * i1;  im[j] = c * i1 + s * r1;
                }
            }
            // CNOT chain (q,q+1): swap amplitudes where control=1, within target pair
#pragma unroll
            for (int qq = 0; qq < 3; ++qq) {
                const int mc = 8 >> qq, mt = 8 >> (qq + 1);
#pragma unroll
                for (int i = 0; i < 16; ++i) if ((i & mc) && !(i & mt)) {
                    const int j = i | mt;
                    float tr = re[i]; re[i] = re[j]; re[j] = tr;
                    float ti = im[i]; im[i] = im[j]; im[j] = ti;
                }
            }
        }
#pragma unroll
        for (int k = 0; k < 16; ++k) { Ur[k][tid] = re[k]; Ui[k][tid] = im[k]; }
    }
    __syncthreads();

    // ---- step 2: M[j][l] = sum_k sign_q(k) Re(U[k,j] conj(U[k,l])) ----
    {
        const int j = tid >> 4, l = tid & 15;
        float acc = 0.0f;
#pragma unroll
        for (int k = 0; k < 16; ++k) {
            const float sgn = ((k >> (3 - q)) & 1) ? -1.0f : 1.0f;
            acc += sgn * (Ur[k][j] * Ur[k][l] + Ui[k][j] * Ui[k][l]);
        }
        M[j][l] = acc;
    }
    __syncthreads();

    // ---- step 3: project onto (1,cos,sin)^{(x)4} basis: 81 coeffs ----
    // per-qubit pair table: a=0 -> (0,0,+),(1,1,+); a=1 -> (0,0,+),(1,1,-);
    // a=2 -> (0,1,+),(1,0,+). Magnitude 0.5 each -> global 1/16.
    if (tid < 81) {
        int ap[4];
        ap[0] = tid / 27; ap[1] = (tid / 9) % 3; ap[2] = (tid / 3) % 3; ap[3] = tid % 3;
        float acc = 0.0f;
        for (int m = 0; m < 16; ++m) {
            int j = 0, l = 0; float sgn = 1.0f;
#pragma unroll
            for (int p = 0; p < 4; ++p) {
                const int o = (m >> (3 - p)) & 1;
                int jb = o, lb = (ap[p] == 2) ? (o ^ 1) : o;
                if (ap[p] == 1 && o) sgn = -sgn;
                j = (j << 1) | jb; l = (l << 1) | lb;
            }
            acc += sgn * M[j][l];
        }
        C[q * 81 + tid] = acc * 0.0625f;
    }
}

__global__ __launch_bounds__(256) void qmain(const float* __restrict__ x,
                                             const float* __restrict__ C,
                                             float* __restrict__ out, int B) {
    const int b = blockIdx.x * 256 + threadIdx.x;
    if (b >= B) return;

    const float4 xv = *reinterpret_cast<const float4*>(x + (size_t)b * 8);
    float xs[4] = {xv.x, xv.y, xv.z, xv.w};
    float cg[4], sg[4];
#pragma unroll
    for (int q = 0; q < 4; ++q) {
        const float e = __expf(2.0f * xs[q]);
        const float t = 1.0f - __fdividef(2.0f, e + 1.0f);   // tanh(x)
        const float th = 3.1415f * t;
        cg[q] = __cosf(th);
        sg[q] = __sinf(th);
    }

    float ev[4];
#pragma unroll
    for (int q = 0; q < 4; ++q) {
        const float* __restrict__ Cq = C + q * 81;
        float r27[27];
#pragma unroll
        for (int m = 0; m < 27; ++m)
            r27[m] = Cq[3 * m] + Cq[3 * m + 1] * cg[3] + Cq[3 * m + 2] * sg[3];
        float r9[9];
#pragma unroll
        for (int m = 0; m < 9; ++m)
            r9[m] = r27[3 * m] + r27[3 * m + 1] * cg[2] + r27[3 * m + 2] * sg[2];
        float r3[3];
#pragma unroll
        for (int m = 0; m < 3; ++m)
            r3[m] = r9[3 * m] + r9[3 * m + 1] * cg[1] + r9[3 * m + 2] * sg[1];
        ev[q] = r3[0] + r3[1] * cg[0] + r3[2] * sg[0];
    }

    *reinterpret_cast<float4*>(out + (size_t)b * 4) = make_float4(ev[0], ev[1], ev[2], ev[3]);
}

extern "C" void kernel_launch(void* const* d_in, const int* in_sizes, int n_in,
                              void* d_out, int out_size, void* d_ws, size_t ws_size,
                              hipStream_t stream) {
    const float* x = (const float*)d_in[0];       // (B, 8) f32
    const float* w = (const float*)d_in[1];       // (2, 4, 3) f32
    float* out = (float*)d_out;                   // (B, 4) f32
    float* C = (float*)d_ws;                      // 4*81 floats scratch

    const int B = in_sizes[0] / 8;

    qsetup<<<4, 256, 0, stream>>>(w, C);
    qmain<<<(B + 255) / 256, 256, 0, stream>>>(x, C, out, B);
}